// Round 7
// baseline (279.314 us; speedup 1.0000x reference)
//
#include <hip/hip_runtime.h>

#define H 768
#define F 3072
#define NE 8
#define T 4096
#define NA 8192      // T * K assignments
#define TP 9216      // padded slot capacity (128-aligned per expert; max 71*128+pad)
#define NRB 72       // max 128-row blocks

typedef unsigned short ushort_t;
typedef __attribute__((ext_vector_type(8))) short bfx8;
typedef __attribute__((ext_vector_type(4))) float fx4;
typedef __attribute__((address_space(3))) const ushort_t lus;

__device__ __forceinline__ ushort_t f2bf(float f) {
    union { float f; unsigned u; } v; v.f = f;
    unsigned u = v.u;
    unsigned r = (u + 0x7fffu + ((u >> 16) & 1u)) >> 16;
    return (ushort_t)r;
}

__device__ __forceinline__ float gelu_tanh(float x) {
    const float c = 0.7978845608028654f;
    float z = c * (x + 0.044715f * x * x * x);
    float t = 1.0f - 2.0f / (__expf(2.0f * z) + 1.0f);   // tanh(z)
    return 0.5f * x * (1.0f + t);
}

__device__ __forceinline__ void g2l16(const void* g, void* l) {
    __builtin_amdgcn_global_load_lds(
        (__attribute__((address_space(1))) void*)g,
        (__attribute__((address_space(3))) void*)l, 16, 0, 0);
}

__device__ __forceinline__ bfx8 dsr128(lus* p) {
    bfx8 r;
    asm volatile("ds_read_b128 %0, %1" : "=v"(r) : "v"(p));
    return r;
}

#define WAITV12 asm volatile("s_waitcnt vmcnt(12)" ::: "memory")
#define WAITV0  asm volatile("s_waitcnt vmcnt(0)" ::: "memory")
#define LGKM12  asm volatile("s_waitcnt lgkmcnt(12)" ::: "memory")
#define LGKM0   asm volatile("s_waitcnt lgkmcnt(0)" ::: "memory")
#define SBAR    asm volatile("s_barrier" ::: "memory")
#define SCHED0  __builtin_amdgcn_sched_barrier(0)
#define PRIO1   __builtin_amdgcn_s_setprio(1)
#define PRIO0   __builtin_amdgcn_s_setprio(0)

// ---------------- router: one wave per token ----------------
__global__ void router_k(const float* __restrict__ x, const float* __restrict__ gw,
                         int* __restrict__ tidx, float* __restrict__ twgt) {
    int t = blockIdx.x * 4 + (threadIdx.x >> 6);
    int lane = threadIdx.x & 63;
    const float* xr = x + (size_t)t * H;
    float acc[NE];
#pragma unroll
    for (int e = 0; e < NE; ++e) acc[e] = 0.f;
    for (int h = lane; h < H; h += 64) {
        float xv = xr[h];
        const float* g = gw + h * NE;
#pragma unroll
        for (int e = 0; e < NE; ++e) acc[e] += xv * g[e];
    }
#pragma unroll
    for (int off = 32; off > 0; off >>= 1) {
#pragma unroll
        for (int e = 0; e < NE; ++e) acc[e] += __shfl_down(acc[e], off);
    }
    if (lane == 0) {
        float l0 = -1e30f, l1 = -1e30f; int i0 = 0, i1 = 0;
#pragma unroll
        for (int e = 0; e < NE; ++e) {
            float v = acc[e];
            if (v > l0) { l1 = l0; i1 = i0; l0 = v; i0 = e; }
            else if (v > l1) { l1 = v; i1 = e; }
        }
        float w0 = 1.f / (1.f + __expf(l1 - l0));
        tidx[t * 2] = i0; tidx[t * 2 + 1] = i1;
        twgt[t * 2] = w0; twgt[t * 2 + 1] = 1.f - w0;
    }
}

__global__ void init_k(int* counts, int* tos) {
    int i = blockIdx.x * 256 + threadIdx.x;
    if (i < NE) counts[i] = 0;
    if (i < TP) tos[i] = -1;
}

__global__ void count_k(const int* __restrict__ tidx, int* counts) {
    int i = blockIdx.x * 256 + threadIdx.x;
    if (i < NA) atomicAdd(&counts[tidx[i]], 1);
}

__global__ void offsets_k(const int* __restrict__ counts, int* cursor,
                          int* rbe, int* rbs) {
    int off = 0, rb = 0;
    for (int e = 0; e < NE; ++e) {
        cursor[e] = off;
        int nrb = (counts[e] + 127) / 128;
        for (int j = 0; j < nrb; ++j) { rbe[rb] = e; rbs[rb] = off + j * 128; ++rb; }
        off += nrb * 128;
    }
    for (; rb < NRB; ++rb) rbe[rb] = -1;
}

__global__ void scatter_k(const int* __restrict__ tidx, int* cursor,
                          int* __restrict__ tos, int* __restrict__ aslot) {
    int i = blockIdx.x * 256 + threadIdx.x;
    if (i < NA) {
        int e = tidx[i];
        int slot = atomicAdd(&cursor[e], 1);
        tos[slot] = i >> 1;
        aslot[i] = slot;
    }
}

// gather selected token rows -> bf16, zeros for padding slots
__global__ void gather_k(const float* __restrict__ x, const int* __restrict__ tos,
                         ushort_t* __restrict__ xg) {
    int i = blockIdx.x * 256 + threadIdx.x;    // TP * (H/8)
    int slot = i / (H / 8);
    int j = i % (H / 8);
    int tok = tos[slot];
    ushort_t v[8];
    if (tok < 0) {
#pragma unroll
        for (int q = 0; q < 8; ++q) v[q] = 0;
    } else {
        const float* src = x + (size_t)tok * H + j * 8;
#pragma unroll
        for (int q = 0; q < 8; ++q) v[q] = f2bf(src[q]);
    }
    *(bfx8*)&xg[(size_t)slot * H + j * 8] = *(const bfx8*)v;
}

// fp32 [R][C] -> bf16 [C][R], per expert (blockIdx.z)
__global__ void transpose_cast_k(const float* __restrict__ src, ushort_t* __restrict__ dst,
                                 int R, int C) {
    int e = blockIdx.z;
    src += (size_t)e * R * C;
    dst += (size_t)e * R * C;
    int c0 = blockIdx.x * 64, r0 = blockIdx.y * 64;
    __shared__ float tile[64][65];
    int tid = threadIdx.x;
    int cc = tid & 63, rr = tid >> 6;    // rr 0..3
#pragma unroll
    for (int rep = 0; rep < 16; ++rep) {
        int r = rep * 4 + rr;
        tile[r][cc] = src[(size_t)(r0 + r) * C + c0 + cc];
    }
    __syncthreads();
#pragma unroll
    for (int rep = 0; rep < 16; ++rep) {
        int c = rep * 4 + rr;
        dst[(size_t)(c0 + c) * R + r0 + cc] = f2bf(tile[cc][c]);
    }
}

// ===== 128x256 x BK64 GEMM, 4 waves (wave tile 64x128), 2-stage LDS =====
// A: [TP][K] bf16 row-major; Bt: [NE][N][K] bf16; C: [TP][N]
// EXPERIMENT (R7): fewer, fatter waves per sync — 64 MFMA/wave between
// barriers (2x R6), 4-wave barrier (was 8). Per iter:
//   WAITV12 (tile t pre-landed) -> SBAR -> 24 asm ds_read (kk0 then kk1)
//   -> LGKM12 -> 32 MFMA kk0 -> LGKM0 -> 32 MFMA kk1 -> SBAR ->
//   STAGE tile t+2 into the buffer just read (all waves past their reads).
// Ledger: 12 loads/tile/wave; steady-state outstanding at entry = 24
// (t,t+1); WAITV12 drains t. Final tile: WAITV0 (only 12 outstanding).
// T2 swizzle (verified R1-R6): row r chunk c stored at slot c^(r&7);
// pre-swizzled global source + same XOR on ds_read.
template <int DO_GELU>
__global__ __launch_bounds__(256, 1)
void gemm_tile_k(const ushort_t* __restrict__ A, const ushort_t* __restrict__ Bt,
                 const float* __restrict__ bias, void* __restrict__ Cout,
                 const int* __restrict__ rbe, const int* __restrict__ rbs,
                 int K, int N, int ncb) {
    constexpr int BUFS = 24576;                      // (128+256)*64 ushorts
    int nwg = gridDim.x, bid = blockIdx.x;
    int wgid = (bid & 7) * (nwg >> 3) + (bid >> 3);  // XCD chunking (nwg%8==0)
    int rb = wgid / ncb, cb = wgid % ncb;
    int e = rbe[rb];
    if (e < 0) return;
    int slot0 = rbs[rb];

    __shared__ __align__(16) ushort_t lds[2 * BUFS];   // 96 KiB

    int tid = threadIdx.x, lane = tid & 63, wid = tid >> 6;
    int wm = wid >> 1, wn = wid & 1;                 // 2M x 2N waves
    int l15 = lane & 15, qh = lane >> 4, sw = l15 & 7;

    const ushort_t* Ab = A + (size_t)slot0 * K;
    const ushort_t* Bb = Bt + ((size_t)e * N + cb * 256) * K;

    // staging: thread -> (row j, chunk q), source chunk pre-swizzled
    int j = tid >> 3, q = tid & 7;                   // j 0..31
    int cs = (q ^ (j & 7)) * 8;
    int ldsw = wid * 512;                            // wave-uniform dst in unit
    const ushort_t* aSrc = Ab + (size_t)j * K + cs;
    const ushort_t* bSrc = Bb + (size_t)j * K + cs;

    // ds_read bases
    int ch0 = (qh ^ sw) << 3;
    int ch1 = ((4 + qh) ^ sw) << 3;
    int abase = (wm * 64 + l15) * 64;                // + m*1024 + chX
    int bbase = 8192 + (wn * 128 + l15) * 64;        // + n*1024 + chX

#define STAGE_T(BUF, KT) do { \
    _Pragma("unroll") for (int u = 0; u < 4; ++u) \
        g2l16(aSrc + (size_t)u * 32 * K + (KT) * 64, \
              &lds[(BUF) * BUFS + u * 2048 + ldsw]); \
    _Pragma("unroll") for (int u = 0; u < 8; ++u) \
        g2l16(bSrc + (size_t)u * 32 * K + (KT) * 64, \
              &lds[(BUF) * BUFS + 8192 + u * 2048 + ldsw]); \
} while (0)

    fx4 acc[4][8];
#pragma unroll
    for (int m = 0; m < 4; ++m)
#pragma unroll
        for (int n = 0; n < 8; ++n) acc[m][n] = (fx4){0.f, 0.f, 0.f, 0.f};
    bfx8 a0[4], a1[4], b0v[8], b1v[8];

    int NT = K >> 6;   // 12 or 48 (even)
    STAGE_T(0, 0);
    STAGE_T(1, 1);

#define KBODY(BUF, TT) do { \
    if ((TT) + 1 < NT) { WAITV12; } else { WAITV0; } \
    SBAR; \
    { \
      int ab = (BUF) * BUFS + abase, bb = (BUF) * BUFS + bbase; \
      _Pragma("unroll") for (int m = 0; m < 4; ++m) a0[m] = dsr128((lus*)&lds[ab + m * 1024 + ch0]); \
      _Pragma("unroll") for (int n = 0; n < 8; ++n) b0v[n] = dsr128((lus*)&lds[bb + n * 1024 + ch0]); \
      _Pragma("unroll") for (int m = 0; m < 4; ++m) a1[m] = dsr128((lus*)&lds[ab + m * 1024 + ch1]); \
      _Pragma("unroll") for (int n = 0; n < 8; ++n) b1v[n] = dsr128((lus*)&lds[bb + n * 1024 + ch1]); \
    } \
    LGKM12; SCHED0; \
    PRIO1; \
    _Pragma("unroll") for (int m = 0; m < 4; ++m) \
    _Pragma("unroll") for (int n = 0; n < 8; ++n) \
        acc[m][n] = __builtin_amdgcn_mfma_f32_16x16x32_bf16(a0[m], b0v[n], acc[m][n], 0, 0, 0); \
    PRIO0; \
    LGKM0; SCHED0; \
    PRIO1; \
    _Pragma("unroll") for (int m = 0; m < 4; ++m) \
    _Pragma("unroll") for (int n = 0; n < 8; ++n) \
        acc[m][n] = __builtin_amdgcn_mfma_f32_16x16x32_bf16(a1[m], b1v[n], acc[m][n], 0, 0, 0); \
    PRIO0; \
    SBAR; \
    if ((TT) + 2 < NT) STAGE_T(BUF, (TT) + 2); \
} while (0)

    for (int t = 0; t < NT; t += 2) {
        KBODY(0, t);
        KBODY(1, t + 1);
    }
#undef KBODY
#undef STAGE_T

    // epilogue: C/D layout col=lane&15, row=(lane>>4)*4+reg (verified)
#pragma unroll
    for (int n = 0; n < 8; ++n) {
        int col = cb * 256 + wn * 128 + n * 16 + l15;
        float bvv = bias[(size_t)e * N + col];
#pragma unroll
        for (int m = 0; m < 4; ++m) {
            int rowb = slot0 + wm * 64 + m * 16 + qh * 4;
            fx4 v = acc[m][n];
#pragma unroll
            for (int jj = 0; jj < 4; ++jj) {
                float val = v[jj] + bvv;
                if (DO_GELU) {
                    ((ushort_t*)Cout)[(size_t)(rowb + jj) * N + col] = f2bf(gelu_tanh(val));
                } else {
                    ((float*)Cout)[(size_t)(rowb + jj) * N + col] = val;
                }
            }
        }
    }
}

// out[t] = w0 * y[slot0] + w1 * y[slot1]
__global__ void combine_k(const float* __restrict__ y, const int* __restrict__ aslot,
                          const float* __restrict__ twgt, float* __restrict__ out) {
    int i = blockIdx.x * 256 + threadIdx.x;   // T * (H/4)
    int t = i / (H / 4);
    int j = i % (H / 4);
    int s0 = aslot[t * 2], s1 = aslot[t * 2 + 1];
    float w0 = twgt[t * 2], w1 = twgt[t * 2 + 1];
    const float4 a = ((const float4*)(y + (size_t)s0 * H))[j];
    const float4 b = ((const float4*)(y + (size_t)s1 * H))[j];
    float4 r;
    r.x = w0 * a.x + w1 * b.x;
    r.y = w0 * a.y + w1 * b.y;
    r.z = w0 * a.z + w1 * b.z;
    r.w = w0 * a.w + w1 * b.w;
    ((float4*)(out + (size_t)t * H))[j] = r;
}

extern "C" void kernel_launch(void* const* d_in, const int* in_sizes, int n_in,
                              void* d_out, int out_size, void* d_ws, size_t ws_size,
                              hipStream_t stream) {
    const float* x  = (const float*)d_in[0];
    const float* gw = (const float*)d_in[1];
    const float* W1 = (const float*)d_in[2];
    const float* b1 = (const float*)d_in[3];
    const float* W2 = (const float*)d_in[4];
    const float* b2 = (const float*)d_in[5];
    float* out = (float*)d_out;

    char* ws = (char*)d_ws;
    size_t o = 0;
    auto carve = [&](size_t bytes) -> void* {
        o = (o + 255) & ~(size_t)255;
        void* p = ws + o;
        o += bytes;
        return p;
    };
    int*      tidx   = (int*)carve((size_t)NA * 4);
    float*    twgt   = (float*)carve((size_t)NA * 4);
    int*      counts = (int*)carve(NE * 4);
    int*      cursor = (int*)carve(NE * 4);
    int*      rbe    = (int*)carve(NRB * 4);
    int*      rbs    = (int*)carve(NRB * 4);
    int*      aslot  = (int*)carve((size_t)NA * 4);
    int*      tos    = (int*)carve((size_t)TP * 4);
    ushort_t* xg     = (ushort_t*)carve((size_t)TP * H * 2);
    ushort_t* w1t    = (ushort_t*)carve((size_t)NE * H * F * 2);
    ushort_t* w2t    = (ushort_t*)carve((size_t)NE * H * F * 2);
    ushort_t* hbuf   = (ushort_t*)carve((size_t)TP * F * 2);
    // ybuf overlays xg (+w1t head) — xg/w1t are dead once GEMM2 runs.
    float*    ybuf   = (float*)xg;
    (void)in_sizes; (void)n_in; (void)out_size; (void)ws_size;

    hipLaunchKernelGGL(init_k, dim3(TP / 256), dim3(256), 0, stream, counts, tos);
    hipLaunchKernelGGL(router_k, dim3(T / 4), dim3(256), 0, stream, x, gw, tidx, twgt);
    hipLaunchKernelGGL(count_k, dim3(NA / 256), dim3(256), 0, stream, tidx, counts);
    hipLaunchKernelGGL(offsets_k, dim3(1), dim3(1), 0, stream, counts, cursor, rbe, rbs);
    hipLaunchKernelGGL(scatter_k, dim3(NA / 256), dim3(256), 0, stream, tidx, cursor, tos, aslot);
    hipLaunchKernelGGL(gather_k, dim3(TP * (H / 8) / 256), dim3(256), 0, stream, x, tos, xg);
    hipLaunchKernelGGL(transpose_cast_k, dim3(F / 64, H / 64, NE), dim3(256), 0, stream, W1, w1t, H, F);
    hipLaunchKernelGGL(transpose_cast_k, dim3(H / 64, F / 64, NE), dim3(256), 0, stream, W2, w2t, F, H);
    // GEMM1: 128M x 256N, K=H=768  -> grid 72*12=864 (~3.4 rounds at 1/CU)
    hipLaunchKernelGGL((gemm_tile_k<1>), dim3(NRB * (F / 256)), dim3(256), 0, stream,
                       xg, w1t, b1, (void*)hbuf, rbe, rbs, H, F, F / 256);
    // GEMM2: 128M x 256N, K=F=3072 -> grid 72*3=216 (~84% fill, 1 round)
    hipLaunchKernelGGL((gemm_tile_k<0>), dim3(NRB * (H / 256)), dim3(256), 0, stream,
                       hbuf, w2t, b2, (void*)ybuf, rbe, rbs, F, H, H / 256);
    hipLaunchKernelGGL(combine_k, dim3(T * (H / 4) / 256), dim3(256), 0, stream,
                       ybuf, aslot, twgt, out);
}

// Round 8
// 250.973 us; speedup vs baseline: 1.1129x; 1.1129x over previous
//
#include <hip/hip_runtime.h>

#define H 768
#define F 3072
#define NE 8
#define T 4096
#define NA 8192      // T * K assignments
#define TP 9216      // padded slot capacity (128-aligned per expert)
#define NRB 72       // max 128-row blocks

typedef unsigned short ushort_t;
typedef __attribute__((ext_vector_type(8))) short bfx8;
typedef __attribute__((ext_vector_type(4))) float fx4;
typedef __attribute__((address_space(3))) const ushort_t lus;

__device__ __forceinline__ ushort_t f2bf(float f) {
    union { float f; unsigned u; } v; v.f = f;
    unsigned u = v.u;
    unsigned r = (u + 0x7fffu + ((u >> 16) & 1u)) >> 16;
    return (ushort_t)r;
}

__device__ __forceinline__ float gelu_tanh(float x) {
    const float c = 0.7978845608028654f;
    float z = c * (x + 0.044715f * x * x * x);
    float t = 1.0f - 2.0f / (__expf(2.0f * z) + 1.0f);   // tanh(z)
    return 0.5f * x * (1.0f + t);
}

__device__ __forceinline__ void g2l16(const void* g, void* l) {
    __builtin_amdgcn_global_load_lds(
        (__attribute__((address_space(1))) void*)g,
        (__attribute__((address_space(3))) void*)l, 16, 0, 0);
}

__device__ __forceinline__ bfx8 dsr128(lus* p) {
    bfx8 r;
    asm volatile("ds_read_b128 %0, %1" : "=v"(r) : "v"(p));
    return r;
}

#define WAITV4 asm volatile("s_waitcnt vmcnt(4)" ::: "memory")
#define WAITV0 asm volatile("s_waitcnt vmcnt(0)" ::: "memory")
#define LGKM6  asm volatile("s_waitcnt lgkmcnt(6)" ::: "memory")
#define LGKM0  asm volatile("s_waitcnt lgkmcnt(0)" ::: "memory")
#define SBAR   asm volatile("s_barrier" ::: "memory")
#define SCHED0 __builtin_amdgcn_sched_barrier(0)
#define PRIO1  __builtin_amdgcn_s_setprio(1)
#define PRIO0  __builtin_amdgcn_s_setprio(0)

// ---------------- router: one wave per token ----------------
__global__ void router_k(const float* __restrict__ x, const float* __restrict__ gw,
                         int* __restrict__ tidx, float* __restrict__ twgt) {
    int t = blockIdx.x * 4 + (threadIdx.x >> 6);
    int lane = threadIdx.x & 63;
    const float* xr = x + (size_t)t * H;
    float acc[NE];
#pragma unroll
    for (int e = 0; e < NE; ++e) acc[e] = 0.f;
    for (int h = lane; h < H; h += 64) {
        float xv = xr[h];
        const float* g = gw + h * NE;
#pragma unroll
        for (int e = 0; e < NE; ++e) acc[e] += xv * g[e];
    }
#pragma unroll
    for (int off = 32; off > 0; off >>= 1) {
#pragma unroll
        for (int e = 0; e < NE; ++e) acc[e] += __shfl_down(acc[e], off);
    }
    if (lane == 0) {
        float l0 = -1e30f, l1 = -1e30f; int i0 = 0, i1 = 0;
#pragma unroll
        for (int e = 0; e < NE; ++e) {
            float v = acc[e];
            if (v > l0) { l1 = l0; i1 = i0; l0 = v; i0 = e; }
            else if (v > l1) { l1 = v; i1 = e; }
        }
        float w0 = 1.f / (1.f + __expf(l1 - l0));
        tidx[t * 2] = i0; tidx[t * 2 + 1] = i1;
        twgt[t * 2] = w0; twgt[t * 2 + 1] = 1.f - w0;
    }
}

__global__ void init_k(int* counts, int* tos) {
    int i = blockIdx.x * 256 + threadIdx.x;
    if (i < NE) counts[i] = 0;
    if (i < TP) tos[i] = -1;
}

__global__ void count_k(const int* __restrict__ tidx, int* counts) {
    int i = blockIdx.x * 256 + threadIdx.x;
    if (i < NA) atomicAdd(&counts[tidx[i]], 1);
}

__global__ void offsets_k(const int* __restrict__ counts, int* cursor,
                          int* rbe, int* rbs) {
    int off = 0, rb = 0;
    for (int e = 0; e < NE; ++e) {
        cursor[e] = off;
        int nrb = (counts[e] + 127) / 128;
        for (int j = 0; j < nrb; ++j) { rbe[rb] = e; rbs[rb] = off + j * 128; ++rb; }
        off += nrb * 128;
    }
    for (; rb < NRB; ++rb) rbe[rb] = -1;
}

__global__ void scatter_k(const int* __restrict__ tidx, int* cursor,
                          int* __restrict__ tos, int* __restrict__ aslot) {
    int i = blockIdx.x * 256 + threadIdx.x;
    if (i < NA) {
        int e = tidx[i];
        int slot = atomicAdd(&cursor[e], 1);
        tos[slot] = i >> 1;
        aslot[i] = slot;
    }
}

// gather selected token rows -> bf16, zeros for padding slots
__global__ void gather_k(const float* __restrict__ x, const int* __restrict__ tos,
                         ushort_t* __restrict__ xg) {
    int i = blockIdx.x * 256 + threadIdx.x;    // TP * (H/8)
    int slot = i / (H / 8);
    int j = i % (H / 8);
    int tok = tos[slot];
    ushort_t v[8];
    if (tok < 0) {
#pragma unroll
        for (int q = 0; q < 8; ++q) v[q] = 0;
    } else {
        const float* src = x + (size_t)tok * H + j * 8;
#pragma unroll
        for (int q = 0; q < 8; ++q) v[q] = f2bf(src[q]);
    }
    *(bfx8*)&xg[(size_t)slot * H + j * 8] = *(const bfx8*)v;
}

// fp32 [R][C] -> bf16 [C][R], per expert (blockIdx.z)
__global__ void transpose_cast_k(const float* __restrict__ src, ushort_t* __restrict__ dst,
                                 int R, int C) {
    int e = blockIdx.z;
    src += (size_t)e * R * C;
    dst += (size_t)e * R * C;
    int c0 = blockIdx.x * 64, r0 = blockIdx.y * 64;
    __shared__ float tile[64][65];
    int tid = threadIdx.x;
    int cc = tid & 63, rr = tid >> 6;    // rr 0..3
#pragma unroll
    for (int rep = 0; rep < 16; ++rep) {
        int r = rep * 4 + rr;
        tile[r][cc] = src[(size_t)(r0 + r) * C + c0 + cc];
    }
    __syncthreads();
#pragma unroll
    for (int rep = 0; rep < 16; ++rep) {
        int c = rep * 4 + rr;
        dst[(size_t)(c0 + c) * R + r0 + cc] = f2bf(tile[cc][c]);
    }
}

// ===== 128x128 x BK64 GEMM, 8 waves (wave tile 64x32), 2-stage LDS =====
// R8 EXPERIMENT: force >=2 independent staging streams per CU.
//   - LDS 64 KiB (2 bufs x 32KB) -> 2 blocks/CU by LDS
//   - 8 waves x acc[4][2] (32 acc regs) + launch_bounds(512,4) caps regs
//     at 128/wave -> 16 waves/CU resource-legal
// Schedule per K-tile (R7-proven ledger, 4 loads/wave/tile):
//   WAITV4 (tile t landed) -> SBAR -> 12 asm ds_read -> LGKM6 ->
//   8 MFMA kk0 -> LGKM0 -> 8 MFMA kk1 -> SBAR -> STAGE(t+2, same buf).
// Outstanding at WAITV: t(4)+t+1(4)=8 -> WAITV4 drains t. Last: WAITV0.
// T2 swizzle (verified R1-R7): row r chunk c at slot c^(r&7), both sides.
template <int DO_GELU>
__global__ __launch_bounds__(512, 4)
void gemm_tile_k(const ushort_t* __restrict__ A, const ushort_t* __restrict__ Bt,
                 const float* __restrict__ bias, void* __restrict__ Cout,
                 const int* __restrict__ rbe, const int* __restrict__ rbs,
                 int K, int N, int ncb) {
    constexpr int BUFS = 16384;                      // (128+128)*64 ushorts
    int nwg = gridDim.x, bid = blockIdx.x;
    int wgid = (bid & 7) * (nwg >> 3) + (bid >> 3);  // XCD chunking (nwg%8==0)
    int rb = wgid / ncb, cb = wgid % ncb;
    int e = rbe[rb];
    if (e < 0) return;
    int slot0 = rbs[rb];

    __shared__ __align__(16) ushort_t lds[2 * BUFS];   // 64 KiB

    int tid = threadIdx.x, lane = tid & 63, wid = tid >> 6;
    int wm = wid >> 2, wn = wid & 3;                 // 2M x 4N waves
    int l15 = lane & 15, qh = lane >> 4, sw = l15 & 7;

    const ushort_t* Ab = A + (size_t)slot0 * K;
    const ushort_t* Bb = Bt + ((size_t)e * N + cb * 128) * K;

    // staging: thread -> (row j 0..63, chunk q), source chunk pre-swizzled
    int j = tid >> 3, q = tid & 7;
    int cs = (q ^ (j & 7)) * 8;
    int ldsw = wid * 512;                            // wave-uniform dst in unit
    const ushort_t* aSrc = Ab + (size_t)j * K + cs;
    const ushort_t* bSrc = Bb + (size_t)j * K + cs;

    // ds_read bases
    int ch0 = (qh ^ sw) << 3;
    int ch1 = ((4 + qh) ^ sw) << 3;
    int abase = (wm * 64 + l15) * 64;                // + m*1024 + chX
    int bbase = 8192 + (wn * 32 + l15) * 64;         // + n*1024 + chX

#define STAGE_T(BUF, KT) do { \
    _Pragma("unroll") for (int u = 0; u < 2; ++u) \
        g2l16(aSrc + (size_t)u * 64 * K + (KT) * 64, \
              &lds[(BUF) * BUFS + u * 4096 + ldsw]); \
    _Pragma("unroll") for (int u = 0; u < 2; ++u) \
        g2l16(bSrc + (size_t)u * 64 * K + (KT) * 64, \
              &lds[(BUF) * BUFS + 8192 + u * 4096 + ldsw]); \
} while (0)

    fx4 acc[4][2];
#pragma unroll
    for (int m = 0; m < 4; ++m)
#pragma unroll
        for (int n = 0; n < 2; ++n) acc[m][n] = (fx4){0.f, 0.f, 0.f, 0.f};
    bfx8 a0[4], a1[4], b0v[2], b1v[2];

    int NT = K >> 6;   // 12 or 48 (even)
    STAGE_T(0, 0);
    STAGE_T(1, 1);

#define KBODY(BUF, TT) do { \
    if ((TT) + 1 < NT) { WAITV4; } else { WAITV0; } \
    SBAR; \
    { \
      int ab = (BUF) * BUFS + abase, bb = (BUF) * BUFS + bbase; \
      _Pragma("unroll") for (int m = 0; m < 4; ++m) a0[m] = dsr128((lus*)&lds[ab + m * 1024 + ch0]); \
      _Pragma("unroll") for (int n = 0; n < 2; ++n) b0v[n] = dsr128((lus*)&lds[bb + n * 1024 + ch0]); \
      _Pragma("unroll") for (int m = 0; m < 4; ++m) a1[m] = dsr128((lus*)&lds[ab + m * 1024 + ch1]); \
      _Pragma("unroll") for (int n = 0; n < 2; ++n) b1v[n] = dsr128((lus*)&lds[bb + n * 1024 + ch1]); \
    } \
    LGKM6; SCHED0; \
    PRIO1; \
    _Pragma("unroll") for (int m = 0; m < 4; ++m) \
    _Pragma("unroll") for (int n = 0; n < 2; ++n) \
        acc[m][n] = __builtin_amdgcn_mfma_f32_16x16x32_bf16(a0[m], b0v[n], acc[m][n], 0, 0, 0); \
    PRIO0; \
    LGKM0; SCHED0; \
    PRIO1; \
    _Pragma("unroll") for (int m = 0; m < 4; ++m) \
    _Pragma("unroll") for (int n = 0; n < 2; ++n) \
        acc[m][n] = __builtin_amdgcn_mfma_f32_16x16x32_bf16(a1[m], b1v[n], acc[m][n], 0, 0, 0); \
    PRIO0; \
    SBAR; \
    if ((TT) + 2 < NT) STAGE_T(BUF, (TT) + 2); \
} while (0)

    for (int t = 0; t < NT; t += 2) {
        KBODY(0, t);
        KBODY(1, t + 1);
    }
#undef KBODY
#undef STAGE_T

    // epilogue: C/D layout col=lane&15, row=(lane>>4)*4+reg (verified)
#pragma unroll
    for (int n = 0; n < 2; ++n) {
        int col = cb * 128 + wn * 32 + n * 16 + l15;
        float bvv = bias[(size_t)e * N + col];
#pragma unroll
        for (int m = 0; m < 4; ++m) {
            int rowb = slot0 + wm * 64 + m * 16 + qh * 4;
            fx4 v = acc[m][n];
#pragma unroll
            for (int jj = 0; jj < 4; ++jj) {
                float val = v[jj] + bvv;
                if (DO_GELU) {
                    ((ushort_t*)Cout)[(size_t)(rowb + jj) * N + col] = f2bf(gelu_tanh(val));
                } else {
                    ((float*)Cout)[(size_t)(rowb + jj) * N + col] = val;
                }
            }
        }
    }
}

// out[t] = w0 * y[slot0] + w1 * y[slot1]
__global__ void combine_k(const float* __restrict__ y, const int* __restrict__ aslot,
                          const float* __restrict__ twgt, float* __restrict__ out) {
    int i = blockIdx.x * 256 + threadIdx.x;   // T * (H/4)
    int t = i / (H / 4);
    int j = i % (H / 4);
    int s0 = aslot[t * 2], s1 = aslot[t * 2 + 1];
    float w0 = twgt[t * 2], w1 = twgt[t * 2 + 1];
    const float4 a = ((const float4*)(y + (size_t)s0 * H))[j];
    const float4 b = ((const float4*)(y + (size_t)s1 * H))[j];
    float4 r;
    r.x = w0 * a.x + w1 * b.x;
    r.y = w0 * a.y + w1 * b.y;
    r.z = w0 * a.z + w1 * b.z;
    r.w = w0 * a.w + w1 * b.w;
    ((float4*)(out + (size_t)t * H))[j] = r;
}

extern "C" void kernel_launch(void* const* d_in, const int* in_sizes, int n_in,
                              void* d_out, int out_size, void* d_ws, size_t ws_size,
                              hipStream_t stream) {
    const float* x  = (const float*)d_in[0];
    const float* gw = (const float*)d_in[1];
    const float* W1 = (const float*)d_in[2];
    const float* b1 = (const float*)d_in[3];
    const float* W2 = (const float*)d_in[4];
    const float* b2 = (const float*)d_in[5];
    float* out = (float*)d_out;

    char* ws = (char*)d_ws;
    size_t o = 0;
    auto carve = [&](size_t bytes) -> void* {
        o = (o + 255) & ~(size_t)255;
        void* p = ws + o;
        o += bytes;
        return p;
    };
    int*      tidx   = (int*)carve((size_t)NA * 4);
    float*    twgt   = (float*)carve((size_t)NA * 4);
    int*      counts = (int*)carve(NE * 4);
    int*      cursor = (int*)carve(NE * 4);
    int*      rbe    = (int*)carve(NRB * 4);
    int*      rbs    = (int*)carve(NRB * 4);
    int*      aslot  = (int*)carve((size_t)NA * 4);
    int*      tos    = (int*)carve((size_t)TP * 4);
    ushort_t* xg     = (ushort_t*)carve((size_t)TP * H * 2);
    ushort_t* w1t    = (ushort_t*)carve((size_t)NE * H * F * 2);
    ushort_t* w2t    = (ushort_t*)carve((size_t)NE * H * F * 2);
    ushort_t* hbuf   = (ushort_t*)carve((size_t)TP * F * 2);
    // ybuf overlays xg (+w1t head) — xg/w1t are dead once GEMM2 runs.
    float*    ybuf   = (float*)xg;
    (void)in_sizes; (void)n_in; (void)out_size; (void)ws_size;

    hipLaunchKernelGGL(init_k, dim3(TP / 256), dim3(256), 0, stream, counts, tos);
    hipLaunchKernelGGL(router_k, dim3(T / 4), dim3(256), 0, stream, x, gw, tidx, twgt);
    hipLaunchKernelGGL(count_k, dim3(NA / 256), dim3(256), 0, stream, tidx, counts);
    hipLaunchKernelGGL(offsets_k, dim3(1), dim3(1), 0, stream, counts, cursor, rbe, rbs);
    hipLaunchKernelGGL(scatter_k, dim3(NA / 256), dim3(256), 0, stream, tidx, cursor, tos, aslot);
    hipLaunchKernelGGL(gather_k, dim3(TP * (H / 8) / 256), dim3(256), 0, stream, x, tos, xg);
    hipLaunchKernelGGL(transpose_cast_k, dim3(F / 64, H / 64, NE), dim3(256), 0, stream, W1, w1t, H, F);
    hipLaunchKernelGGL(transpose_cast_k, dim3(H / 64, F / 64, NE), dim3(256), 0, stream, W2, w2t, F, H);
    // GEMM1: 128x128 tiles -> grid 72*24=1728 (~3.4 rounds at 2 blocks/CU)
    hipLaunchKernelGGL((gemm_tile_k<1>), dim3(NRB * (F / 128)), dim3(512), 0, stream,
                       xg, w1t, b1, (void*)hbuf, rbe, rbs, H, F, F / 128);
    // GEMM2: 128x128 tiles -> grid 72*6=432 (~0.84 round at 2 blocks/CU)
    hipLaunchKernelGGL((gemm_tile_k<0>), dim3(NRB * (H / 128)), dim3(512), 0, stream,
                       hbuf, w2t, b2, (void*)ybuf, rbe, rbs, F, H, H / 128);
    hipLaunchKernelGGL(combine_k, dim3(T * (H / 4) / 256), dim3(256), 0, stream,
                       ybuf, aslot, twgt, out);
}